// Round 8
// baseline (465.798 us; speedup 1.0000x reference)
//
#include <hip/hip_runtime.h>
#include <hip/hip_fp16.h>

#define NN 8192
#define MM 8192
#define FD 128
#define EDm 128
#define HD 64
#define NH 4

typedef float f32x4 __attribute__((ext_vector_type(4)));
typedef _Float16 h16x8 __attribute__((ext_vector_type(8)));
typedef unsigned int u32;
typedef unsigned long long u64;

// ---------------- fused prep: pack(A) + esrc + e1 in one grid ----------------
// blocks [0,2048): pack A bits (4 waves/block, 1 row/wave)
// blocks [2048,2176): esrc (128 blocks)
// blocks [2176,3200): e1 (1024 blocks)
__global__ void k_prep(const int* __restrict__ A, u32* __restrict__ bitsG,
                       const float* __restrict__ F0, const float* __restrict__ Wf,
                       const float* __restrict__ aa, float* __restrict__ esrc,
                       const float* __restrict__ E0, const float* __restrict__ We,
                       uint4* __restrict__ Bp, _Float16* __restrict__ edh,
                       _Float16* __restrict__ ed2h) {
  __shared__ float vfL[NH * FD];
  const int bid = blockIdx.x;
  const int t = threadIdx.x;          // 256
  const int lane = t & 63;

  if (bid < 2048) {
    // ---- pack: bitsG[n][256] u32, bit for col m at word m>>5, bit m&31 ----
    const int row = bid * 4 + (t >> 6);
    const int* ap = A + (size_t)row * MM + lane;
    u32* op = bitsG + (size_t)row * 256;
#pragma unroll 2
    for (int c = 0; c < 128; c += 8) {
      int v[8];
#pragma unroll
      for (int k = 0; k < 8; ++k)
        v[k] = __builtin_nontemporal_load(ap + (c + k) * 64);
      u64 b[8];
#pragma unroll
      for (int k = 0; k < 8; ++k) b[k] = __ballot(v[k] > 0);
      if (lane == 0) {
#pragma unroll
        for (int k = 0; k < 8; k += 2) {
          uint4 w = {(u32)b[k], (u32)(b[k] >> 32), (u32)b[k + 1], (u32)(b[k + 1] >> 32)};
          *(uint4*)(op + 2 * (c + k)) = w;
        }
      }
    }
  } else if (bid < 2176) {
    // ---- esrc: vf[h][f] = Wf[h][f][:].a[h][:]; esrc[h][n] = F0[n,:].vf[h,:] ----
    const int b2 = bid - 2048;
#pragma unroll
    for (int r = 0; r < 2; ++r) {
      int idx = t + r * 256;
      int h = idx >> 7, f = idx & 127;
      const float* w = Wf + (size_t)(h * FD + f) * HD;
      const float* av = aa + h * HD;
      float s = 0.f;
#pragma unroll
      for (int d = 0; d < HD; ++d) s += w[d] * av[d];
      vfL[idx] = s;
    }
    __syncthreads();
    int g = b2 * 256 + t;             // 0..32767
    int n = g >> 2, h = g & 3;
    const float4* fr = (const float4*)(F0 + (size_t)n * FD);
    const float4* vr = (const float4*)(vfL + h * FD);
    float s = 0.f;
#pragma unroll
    for (int i = 0; i < FD / 4; ++i) {
      float4 x = fr[i], y = vr[i];
      s += x.x * y.x + x.y * y.y + x.z * y.z + x.w * y.w;
    }
    esrc[h * NN + n] = s;
  } else {
    // ---- e1: E1 = E0·We; Bp in MFMA-B fragment order + ed/ed2 fp16 tables ----
    const int wid = (bid - 2176) * 4 + (t >> 6);   // 0..4095
    const int h = wid >> 10;
    const int mg = wid & 1023;
    const int m = mg * 8;
    const float* we = We + (size_t)h * EDm * HD + lane;
    const float* e0r = E0 + (size_t)m * EDm;
    float ac[8] = {};
#pragma unroll 4
    for (int e = 0; e < EDm; ++e) {
      float wv = we[e * HD];
#pragma unroll
      for (int j = 0; j < 8; ++j) ac[j] += e0r[j * EDm + e] * wv;
    }
    int mc = mg >> 2, quad = mg & 3, dt = lane >> 4, col = lane & 15;
    union { h16x8 v; uint4 u; } hv;
#pragma unroll
    for (int j = 0; j < 8; ++j) hv.v[j] = (_Float16)ac[j];
    Bp[(((size_t)h * 256 + mc) * 4 + dt) * 64 + quad * 16 + col] = hv.u;

    float av = aa[h * HD + lane];
    float d[8];
#pragma unroll
    for (int j = 0; j < 8; ++j) d[j] = ac[j] * av;
#pragma unroll
    for (int o = 32; o; o >>= 1)
#pragma unroll
      for (int j = 0; j < 8; ++j) d[j] += __shfl_xor(d[j], o);
    if (lane == 0) {
      const float L2E = 1.4426950408889634f;
      union { h16x8 v; uint4 u; } e1, e2;
#pragma unroll
      for (int j = 0; j < 8; ++j) {
        e1.v[j] = (_Float16)exp2f(d[j] * L2E);
        e2.v[j] = (_Float16)exp2f(0.2f * d[j] * L2E);
      }
      *(uint4*)(edh + (size_t)h * MM + m) = e1.u;
      *(uint4*)(ed2h + (size_t)h * MM + m) = e2.u;
    }
  }
}

// bit b0 at `bit`, b1 at bit+1 -> (b0?0xffff:0)|(b1?0xffff0000:0)
__device__ __forceinline__ u32 hm2b(u32 w, int bit) {
  return (((w >> bit) & 1u) | (((w >> (bit + 1)) & 1u) << 16)) * 0xffffu;
}

// Main (R7 + LDS B-staging): grid = 64 n-tiles x 4 mq (mq = bid&3 -> per-XCD
// Bp slice L2-resident). 1024 thr, 16 waves = 4 heads x 4 rowgroups(32 rows).
// NEW: B-tile (16 KB: 4 heads x 4 KB) staged into a 2x16 KB LDS dbuf ONCE per
// block per iter (each thread 1 uint4, T14 issue-early/write-late), all 4
// rowgroup-waves of a head ds_read it -> in-loop L2 traffic drops 4x
// (64->16 KB/iter) and global loads per wave per iter drop 4 -> 1.
// One barrier per iter. ed/e2 stay in LDS (R7). Masks keep depth-1 prefetch.
__global__ __launch_bounds__(1024, 4) void k_main(
    const u32* __restrict__ bitsG, const uint4* __restrict__ Bp,
    const float* __restrict__ esrc, const _Float16* __restrict__ edh,
    const _Float16* __restrict__ ed2h, float* __restrict__ Npart,
    float* __restrict__ Dpart) {
  __shared__ __align__(16) u32 bits[128 * 68];       // 34816 B
  __shared__ __align__(16) _Float16 edL[NH * 2048];  // 16 KB
  __shared__ __align__(16) _Float16 e2L[NH * 2048];  // 16 KB
  __shared__ __align__(16) uint4 Bst[2][NH * 256];   // 32 KB double buffer

  const int t = threadIdx.x;
  const int lane = t & 63;
  const int wv = t >> 6;       // 0..15
  const int h = wv & 3;        // head
  const int g = wv >> 2;       // rowgroup (32 rows)
  const int col = lane & 15;
  const int quad = lane >> 4;
  const int qs = quad * 8;
  const int mq = blockIdx.x & 3;
  const int n0 = (blockIdx.x >> 2) * 128;
  const float L2E = 1.4426950408889634f;

  // ---- prologue: bits tile + ed/e2 slices -> LDS; stage B tile 0 ----
#pragma unroll
  for (int i = 0; i < 2; ++i) {
    int idx = t + i * 1024;            // 0..2047
    int row = idx >> 4, u4 = idx & 15;
    uint4 v = *(const uint4*)(bitsG + (size_t)(n0 + row) * 256 + mq * 64 + u4 * 4);
    *(uint4*)(bits + row * 68 + u4 * 4) = v;
  }
  {
    int hh = t >> 8;                   // 0..3
    int off = (t & 255) * 8;           // 0..2040
    *(uint4*)(edL + hh * 2048 + off) =
        *(const uint4*)(edh + (size_t)hh * MM + mq * 2048 + off);
    *(uint4*)(e2L + hh * 2048 + off) =
        *(const uint4*)(ed2h + (size_t)hh * MM + mq * 2048 + off);
  }
  // staging role: thread t owns head sh, slot si (wave-contiguous: conflict-free)
  const int sh = t >> 8, si = t & 255;
  const uint4* bpS = Bp + (size_t)sh * 65536 + (size_t)mq * 16384 + si;
  Bst[0][sh * 256 + si] = bpS[0];

  const _Float16* edp = edL + h * 2048 + qs;   // LDS
  const _Float16* e2p = e2L + h * 2048 + qs;   // LDS

  float s0 = esrc[h * NN + n0 + g * 32 + col];
  float s1 = esrc[h * NN + n0 + g * 32 + 16 + col];
  _Float16 e80 = (_Float16)exp2f(0.8f * s0 * L2E);
  _Float16 e81 = (_Float16)exp2f(0.8f * s1 * L2E);
  h16x8 es80 = {e80, e80, e80, e80, e80, e80, e80, e80};
  h16x8 es81 = {e81, e81, e81, e81, e81, e81, e81, e81};
  const h16x8 ones = {(_Float16)1.f, (_Float16)1.f, (_Float16)1.f, (_Float16)1.f,
                      (_Float16)1.f, (_Float16)1.f, (_Float16)1.f, (_Float16)1.f};

  __syncthreads();

  const u32* rd0 = bits + (g * 32 + col) * 68;        // + it
  const u32* rd1 = bits + (g * 32 + 16 + col) * 68;   // + it
  u32 aw0 = rd0[0], aw1 = rd1[0];

  f32x4 acc[2][4] = {};
  f32x4 accd[2] = {};

  int buf = 0;
  for (int it = 0; it < 64; ++it) {
    // issue-early: global load of next B tile into reg (write-late below)
    const int ip = (it < 63) ? it + 1 : 63;  // clamped tail (redundant)
    const uint4 sv = bpS[ip * 256];
    // depth-1 mask prefetch (LDS)
    const u32 naw0 = rd0[ip];
    const u32 naw1 = rd1[ip];

    // consume: B fragments from LDS (conflict-free ds_read_b128)
    const uint4* bb = &Bst[buf][h * 256];
    union { h16x8 v; uint4 u; } w0, w1, b0, b1, b2, b3;
    b0.u = bb[lane];
    b1.u = bb[64 + lane];
    b2.u = bb[128 + lane];
    b3.u = bb[192 + lane];

    // ed/e2 from LDS (broadcast within quad groups)
    const h16x8 edv = *(const h16x8*)(edp + it * 32);
    const h16x8 e2v = *(const h16x8*)(e2p + it * 32);

    uint4 m0, m1;
    m0.x = hm2b(aw0, qs);     m0.y = hm2b(aw0, qs + 2);
    m0.z = hm2b(aw0, qs + 4); m0.w = hm2b(aw0, qs + 6);
    m1.x = hm2b(aw1, qs);     m1.y = hm2b(aw1, qs + 2);
    m1.z = hm2b(aw1, qs + 4); m1.w = hm2b(aw1, qs + 6);

    w0.v = __builtin_elementwise_max(edv * es80, e2v);
    w1.v = __builtin_elementwise_max(edv * es81, e2v);
    w0.u.x &= m0.x; w0.u.y &= m0.y; w0.u.z &= m0.z; w0.u.w &= m0.w;
    w1.u.x &= m1.x; w1.u.y &= m1.y; w1.u.z &= m1.z; w1.u.w &= m1.w;

    acc[0][0] = __builtin_amdgcn_mfma_f32_16x16x32_f16(w0.v, b0.v, acc[0][0], 0, 0, 0);
    acc[1][0] = __builtin_amdgcn_mfma_f32_16x16x32_f16(w1.v, b0.v, acc[1][0], 0, 0, 0);
    acc[0][1] = __builtin_amdgcn_mfma_f32_16x16x32_f16(w0.v, b1.v, acc[0][1], 0, 0, 0);
    acc[1][1] = __builtin_amdgcn_mfma_f32_16x16x32_f16(w1.v, b1.v, acc[1][1], 0, 0, 0);
    acc[0][2] = __builtin_amdgcn_mfma_f32_16x16x32_f16(w0.v, b2.v, acc[0][2], 0, 0, 0);
    acc[1][2] = __builtin_amdgcn_mfma_f32_16x16x32_f16(w1.v, b2.v, acc[1][2], 0, 0, 0);
    acc[0][3] = __builtin_amdgcn_mfma_f32_16x16x32_f16(w0.v, b3.v, acc[0][3], 0, 0, 0);
    acc[1][3] = __builtin_amdgcn_mfma_f32_16x16x32_f16(w1.v, b3.v, acc[1][3], 0, 0, 0);
    accd[0] = __builtin_amdgcn_mfma_f32_16x16x32_f16(w0.v, ones, accd[0], 0, 0, 0);
    accd[1] = __builtin_amdgcn_mfma_f32_16x16x32_f16(w1.v, ones, accd[1], 0, 0, 0);

    // write-late: park next tile in the other buffer, then sync
    Bst[buf ^ 1][sh * 256 + si] = sv;
    __syncthreads();
    buf ^= 1;
    aw0 = naw0; aw1 = naw1;
  }

  // ---- write per-(mq,h) partials; C row = rt*16+quad*4+r2, d = dt*16+col ----
  float* np = Npart + (((size_t)(mq * 4 + h) * NN) + n0 + g * 32) * HD;
#pragma unroll
  for (int rt = 0; rt < 2; ++rt)
#pragma unroll
    for (int dt = 0; dt < 4; ++dt)
#pragma unroll
      for (int r2 = 0; r2 < 4; ++r2)
        np[(size_t)(rt * 16 + quad * 4 + r2) * HD + dt * 16 + col] = acc[rt][dt][r2];
  if (col == 0) {
    float* dp = Dpart + (size_t)(mq * 4 + h) * NN + n0 + g * 32;
#pragma unroll
    for (int rt = 0; rt < 2; ++rt)
#pragma unroll
      for (int r2 = 0; r2 < 4; ++r2)
        dp[rt * 16 + quad * 4 + r2] = accd[rt][r2];
  }
}

// Combine: sum 4 mq-partials, head-mean, row softmax. 1 wave per n-row.
__global__ void k_comb(const float* __restrict__ Npart,
                       const float* __restrict__ Dpart,
                       float* __restrict__ out) {
  const int t = threadIdx.x;           // 256
  const int lane = t & 63;
  const int n = blockIdx.x * 4 + (t >> 6);
  const float L2E = 1.4426950408889634f;

  float v = 0.f;
#pragma unroll
  for (int h = 0; h < NH; ++h) {
    float num = 0.f, den = 0.f;
#pragma unroll
    for (int mq = 0; mq < 4; ++mq) {
      num += Npart[(((size_t)(mq * 4 + h) * NN) + n) * HD + lane];
      den += Dpart[(size_t)(mq * 4 + h) * NN + n];
    }
    v += num / den;
  }
  v *= 0.25f;

  float mx = v;
#pragma unroll
  for (int o = 32; o; o >>= 1) mx = fmaxf(mx, __shfl_xor(mx, o));
  float p = exp2f((v - mx) * L2E);
  float sm = p;
#pragma unroll
  for (int o = 32; o; o >>= 1) sm += __shfl_xor(sm, o);
  out[(size_t)n * HD + lane] = p / sm;
}

extern "C" void kernel_launch(void* const* d_in, const int* in_sizes, int n_in,
                              void* d_out, int out_size, void* d_ws, size_t ws_size,
                              hipStream_t stream) {
  const float* F0 = (const float*)d_in[0];
  const float* E0 = (const float*)d_in[1];
  const int* A = (const int*)d_in[2];
  const float* Wf = (const float*)d_in[3];
  const float* We = (const float*)d_in[4];
  const float* a = (const float*)d_in[5];
  float* out = (float*)d_out;

  char* w = (char*)d_ws;
  float* esrc = (float*)w;        w += (size_t)NH * NN * 4;
  _Float16* edh = (_Float16*)w;   w += (size_t)NH * MM * 2;
  _Float16* ed2h = (_Float16*)w;  w += (size_t)NH * MM * 2;
  uint4* Bp = (uint4*)w;          w += (size_t)NH * HD * MM * 2;
  u32* bitsG = (u32*)w;           w += (size_t)NN * 256 * 4;
  float* Npart = (float*)w;       w += (size_t)16 * NN * HD * 4;
  float* Dpart = (float*)w;       w += (size_t)16 * NN * 4;

  k_prep<<<3200, 256, 0, stream>>>(A, bitsG, F0, Wf, a, esrc, E0, We, Bp, edh, ed2h);
  k_main<<<256, 1024, 0, stream>>>(bitsG, Bp, esrc, edh, ed2h, Npart, Dpart);
  k_comb<<<NN / 4, 256, 0, stream>>>(Npart, Dpart, out);
}

// Round 9
// 447.230 us; speedup vs baseline: 1.0415x; 1.0415x over previous
//
#include <hip/hip_runtime.h>
#include <hip/hip_fp16.h>

#define NN 8192
#define MM 8192
#define FD 128
#define EDm 128
#define HD 64
#define NH 4

typedef float f32x4 __attribute__((ext_vector_type(4)));
typedef _Float16 h16x8 __attribute__((ext_vector_type(8)));
typedef unsigned int u32;
typedef unsigned long long u64;

// ---------------- fused prep: pack(A) + esrc + e1 in one grid ----------------
// blocks [0,2048): pack A bits (4 waves/block, 1 row/wave)
// blocks [2048,2176): esrc (128 blocks)
// blocks [2176,3200): e1 (1024 blocks)
__global__ void k_prep(const int* __restrict__ A, u32* __restrict__ bitsG,
                       const float* __restrict__ F0, const float* __restrict__ Wf,
                       const float* __restrict__ aa, float* __restrict__ esrc,
                       const float* __restrict__ E0, const float* __restrict__ We,
                       uint4* __restrict__ Bp, _Float16* __restrict__ edh,
                       _Float16* __restrict__ ed2h) {
  __shared__ float vfL[NH * FD];
  const int bid = blockIdx.x;
  const int t = threadIdx.x;          // 256
  const int lane = t & 63;

  if (bid < 2048) {
    // ---- pack: bitsG[n][256] u32, bit for col m at word m>>5, bit m&31 ----
    const int row = bid * 4 + (t >> 6);
    const int* ap = A + (size_t)row * MM + lane;
    u32* op = bitsG + (size_t)row * 256;
#pragma unroll 2
    for (int c = 0; c < 128; c += 8) {
      int v[8];
#pragma unroll
      for (int k = 0; k < 8; ++k)
        v[k] = __builtin_nontemporal_load(ap + (c + k) * 64);
      u64 b[8];
#pragma unroll
      for (int k = 0; k < 8; ++k) b[k] = __ballot(v[k] > 0);
      if (lane == 0) {
#pragma unroll
        for (int k = 0; k < 8; k += 2) {
          uint4 w = {(u32)b[k], (u32)(b[k] >> 32), (u32)b[k + 1], (u32)(b[k + 1] >> 32)};
          *(uint4*)(op + 2 * (c + k)) = w;
        }
      }
    }
  } else if (bid < 2176) {
    // ---- esrc: vf[h][f] = Wf[h][f][:].a[h][:]; esrc[h][n] = F0[n,:].vf[h,:] ----
    const int b2 = bid - 2048;
#pragma unroll
    for (int r = 0; r < 2; ++r) {
      int idx = t + r * 256;
      int h = idx >> 7, f = idx & 127;
      const float* w = Wf + (size_t)(h * FD + f) * HD;
      const float* av = aa + h * HD;
      float s = 0.f;
#pragma unroll
      for (int d = 0; d < HD; ++d) s += w[d] * av[d];
      vfL[idx] = s;
    }
    __syncthreads();
    int g = b2 * 256 + t;             // 0..32767
    int n = g >> 2, h = g & 3;
    const float4* fr = (const float4*)(F0 + (size_t)n * FD);
    const float4* vr = (const float4*)(vfL + h * FD);
    float s = 0.f;
#pragma unroll
    for (int i = 0; i < FD / 4; ++i) {
      float4 x = fr[i], y = vr[i];
      s += x.x * y.x + x.y * y.y + x.z * y.z + x.w * y.w;
    }
    esrc[h * NN + n] = s;
  } else {
    // ---- e1: E1 = E0·We; Bp in MFMA-B fragment order + ed/ed2 fp16 tables ----
    const int wid = (bid - 2176) * 4 + (t >> 6);   // 0..4095
    const int h = wid >> 10;
    const int mg = wid & 1023;
    const int m = mg * 8;
    const float* we = We + (size_t)h * EDm * HD + lane;
    const float* e0r = E0 + (size_t)m * EDm;
    float ac[8] = {};
#pragma unroll 4
    for (int e = 0; e < EDm; ++e) {
      float wv = we[e * HD];
#pragma unroll
      for (int j = 0; j < 8; ++j) ac[j] += e0r[j * EDm + e] * wv;
    }
    int mc = mg >> 2, quad = mg & 3, dt = lane >> 4, col = lane & 15;
    union { h16x8 v; uint4 u; } hv;
#pragma unroll
    for (int j = 0; j < 8; ++j) hv.v[j] = (_Float16)ac[j];
    Bp[(((size_t)h * 256 + mc) * 4 + dt) * 64 + quad * 16 + col] = hv.u;

    float av = aa[h * HD + lane];
    float d[8];
#pragma unroll
    for (int j = 0; j < 8; ++j) d[j] = ac[j] * av;
#pragma unroll
    for (int o = 32; o; o >>= 1)
#pragma unroll
      for (int j = 0; j < 8; ++j) d[j] += __shfl_xor(d[j], o);
    if (lane == 0) {
      const float L2E = 1.4426950408889634f;
      union { h16x8 v; uint4 u; } e1, e2;
#pragma unroll
      for (int j = 0; j < 8; ++j) {
        e1.v[j] = (_Float16)exp2f(d[j] * L2E);
        e2.v[j] = (_Float16)exp2f(0.2f * d[j] * L2E);
      }
      *(uint4*)(edh + (size_t)h * MM + m) = e1.u;
      *(uint4*)(ed2h + (size_t)h * MM + m) = e2.u;
    }
  }
}

// bit b0 at `bit`, b1 at bit+1 -> (b0?0xffff:0)|(b1?0xffff0000:0)
__device__ __forceinline__ u32 hm2b(u32 w, int bit) {
  return (((w >> bit) & 1u) | (((w >> (bit + 1)) & 1u) << 16)) * 0xffffu;
}

// Main (R7 structure = proven best 447.9; R8's LDS B-staging reverted -
// per-iter barrier cost > L2 dedup win). grid = 64 n-tiles x 4 mq (mq =
// bid&3 -> per-XCD Bp slice L2-resident). 1024 thr, 16 waves = 4 heads x
// 4 rowgroups(32 rows), 4 waves/SIMD, barrier-free drifting main loop.
// ed/e2 in LDS (R7 win). NEW vs R7: s_setprio(1) around the MFMA cluster
// (drifting-wave regime = where T5 measured +4-7%), #pragma unroll 2 on
// the it-loop, nontemporal Npart stores (don't evict Bp from L2).
__global__ __launch_bounds__(1024, 4) void k_main(
    const u32* __restrict__ bitsG, const uint4* __restrict__ Bp,
    const float* __restrict__ esrc, const _Float16* __restrict__ edh,
    const _Float16* __restrict__ ed2h, float* __restrict__ Npart,
    float* __restrict__ Dpart) {
  __shared__ __align__(16) u32 bits[128 * 68];       // 34816 B
  __shared__ __align__(16) _Float16 edL[NH * 2048];  // 16 KB
  __shared__ __align__(16) _Float16 e2L[NH * 2048];  // 16 KB

  const int t = threadIdx.x;
  const int lane = t & 63;
  const int wv = t >> 6;       // 0..15
  const int h = wv & 3;        // head
  const int g = wv >> 2;       // rowgroup (32 rows)
  const int col = lane & 15;
  const int quad = lane >> 4;
  const int qs = quad * 8;
  const int mq = blockIdx.x & 3;
  const int n0 = (blockIdx.x >> 2) * 128;
  const float L2E = 1.4426950408889634f;

  // ---- prologue: bits tile (128 rows x 64 words) + ed/e2 slices -> LDS ----
#pragma unroll
  for (int i = 0; i < 2; ++i) {
    int idx = t + i * 1024;            // 0..2047
    int row = idx >> 4, u4 = idx & 15;
    uint4 v = *(const uint4*)(bitsG + (size_t)(n0 + row) * 256 + mq * 64 + u4 * 4);
    *(uint4*)(bits + row * 68 + u4 * 4) = v;
  }
  {
    int hh = t >> 8;                   // 0..3
    int off = (t & 255) * 8;           // 0..2040
    *(uint4*)(edL + hh * 2048 + off) =
        *(const uint4*)(edh + (size_t)hh * MM + mq * 2048 + off);
    *(uint4*)(e2L + hh * 2048 + off) =
        *(const uint4*)(ed2h + (size_t)hh * MM + mq * 2048 + off);
  }

  const uint4* bp = Bp + (size_t)h * 65536 + (size_t)mq * 16384 + lane;
  const _Float16* edp = edL + h * 2048 + qs;   // LDS
  const _Float16* e2p = e2L + h * 2048 + qs;   // LDS

  // preload iter 0 B (global; completes during barrier)
  uint4 bu0 = bp[0], bu1 = bp[64], bu2 = bp[128], bu3 = bp[192];

  float s0 = esrc[h * NN + n0 + g * 32 + col];
  float s1 = esrc[h * NN + n0 + g * 32 + 16 + col];
  _Float16 e80 = (_Float16)exp2f(0.8f * s0 * L2E);
  _Float16 e81 = (_Float16)exp2f(0.8f * s1 * L2E);
  h16x8 es80 = {e80, e80, e80, e80, e80, e80, e80, e80};
  h16x8 es81 = {e81, e81, e81, e81, e81, e81, e81, e81};
  const h16x8 ones = {(_Float16)1.f, (_Float16)1.f, (_Float16)1.f, (_Float16)1.f,
                      (_Float16)1.f, (_Float16)1.f, (_Float16)1.f, (_Float16)1.f};

  __syncthreads();

  const u32* rd0 = bits + (g * 32 + col) * 68;        // + it
  const u32* rd1 = bits + (g * 32 + 16 + col) * 68;   // + it
  u32 aw0 = rd0[0], aw1 = rd1[0];

  f32x4 acc[2][4] = {};
  f32x4 accd[2] = {};

#pragma unroll 2
  for (int it = 0; it < 64; ++it) {
    // depth-1 prefetch: B (global) + mask words (LDS); clamped tail reload
    const int ip = (it < 63) ? it + 1 : 63;
    const u32 naw0 = rd0[ip];
    const u32 naw1 = rd1[ip];
    const uint4 nb0 = bp[ip * 256];
    const uint4 nb1 = bp[ip * 256 + 64];
    const uint4 nb2 = bp[ip * 256 + 128];
    const uint4 nb3 = bp[ip * 256 + 192];

    // ed/e2 from LDS (broadcast within quad groups, conflict-free)
    const h16x8 edv = *(const h16x8*)(edp + it * 32);
    const h16x8 e2v = *(const h16x8*)(e2p + it * 32);

    uint4 m0, m1;
    m0.x = hm2b(aw0, qs);     m0.y = hm2b(aw0, qs + 2);
    m0.z = hm2b(aw0, qs + 4); m0.w = hm2b(aw0, qs + 6);
    m1.x = hm2b(aw1, qs);     m1.y = hm2b(aw1, qs + 2);
    m1.z = hm2b(aw1, qs + 4); m1.w = hm2b(aw1, qs + 6);

    union { h16x8 v; uint4 u; } w0, w1, b0, b1, b2, b3;
    b0.u = bu0; b1.u = bu1; b2.u = bu2; b3.u = bu3;
    w0.v = __builtin_elementwise_max(edv * es80, e2v);
    w1.v = __builtin_elementwise_max(edv * es81, e2v);
    w0.u.x &= m0.x; w0.u.y &= m0.y; w0.u.z &= m0.z; w0.u.w &= m0.w;
    w1.u.x &= m1.x; w1.u.y &= m1.y; w1.u.z &= m1.z; w1.u.w &= m1.w;

    __builtin_amdgcn_s_setprio(1);
    acc[0][0] = __builtin_amdgcn_mfma_f32_16x16x32_f16(w0.v, b0.v, acc[0][0], 0, 0, 0);
    acc[1][0] = __builtin_amdgcn_mfma_f32_16x16x32_f16(w1.v, b0.v, acc[1][0], 0, 0, 0);
    acc[0][1] = __builtin_amdgcn_mfma_f32_16x16x32_f16(w0.v, b1.v, acc[0][1], 0, 0, 0);
    acc[1][1] = __builtin_amdgcn_mfma_f32_16x16x32_f16(w1.v, b1.v, acc[1][1], 0, 0, 0);
    acc[0][2] = __builtin_amdgcn_mfma_f32_16x16x32_f16(w0.v, b2.v, acc[0][2], 0, 0, 0);
    acc[1][2] = __builtin_amdgcn_mfma_f32_16x16x32_f16(w1.v, b2.v, acc[1][2], 0, 0, 0);
    acc[0][3] = __builtin_amdgcn_mfma_f32_16x16x32_f16(w0.v, b3.v, acc[0][3], 0, 0, 0);
    acc[1][3] = __builtin_amdgcn_mfma_f32_16x16x32_f16(w1.v, b3.v, acc[1][3], 0, 0, 0);
    accd[0] = __builtin_amdgcn_mfma_f32_16x16x32_f16(w0.v, ones, accd[0], 0, 0, 0);
    accd[1] = __builtin_amdgcn_mfma_f32_16x16x32_f16(w1.v, ones, accd[1], 0, 0, 0);
    __builtin_amdgcn_s_setprio(0);

    aw0 = naw0; aw1 = naw1;
    bu0 = nb0; bu1 = nb1; bu2 = nb2; bu3 = nb3;
  }

  // ---- write per-(mq,h) partials; C row = rt*16+quad*4+r2, d = dt*16+col ----
  // nontemporal: don't let 128 KB of partial writes evict the Bp L2 slice.
  float* np = Npart + (((size_t)(mq * 4 + h) * NN) + n0 + g * 32) * HD;
#pragma unroll
  for (int rt = 0; rt < 2; ++rt)
#pragma unroll
    for (int dt = 0; dt < 4; ++dt)
#pragma unroll
      for (int r2 = 0; r2 < 4; ++r2)
        __builtin_nontemporal_store(
            acc[rt][dt][r2],
            np + (size_t)(rt * 16 + quad * 4 + r2) * HD + dt * 16 + col);
  if (col == 0) {
    float* dp = Dpart + (size_t)(mq * 4 + h) * NN + n0 + g * 32;
#pragma unroll
    for (int rt = 0; rt < 2; ++rt)
#pragma unroll
      for (int r2 = 0; r2 < 4; ++r2)
        dp[rt * 16 + quad * 4 + r2] = accd[rt][r2];
  }
}

// Combine: sum 4 mq-partials, head-mean, row softmax. 1 wave per n-row.
__global__ void k_comb(const float* __restrict__ Npart,
                       const float* __restrict__ Dpart,
                       float* __restrict__ out) {
  const int t = threadIdx.x;           // 256
  const int lane = t & 63;
  const int n = blockIdx.x * 4 + (t >> 6);
  const float L2E = 1.4426950408889634f;

  float v = 0.f;
#pragma unroll
  for (int h = 0; h < NH; ++h) {
    float num = 0.f, den = 0.f;
#pragma unroll
    for (int mq = 0; mq < 4; ++mq) {
      num += Npart[(((size_t)(mq * 4 + h) * NN) + n) * HD + lane];
      den += Dpart[(size_t)(mq * 4 + h) * NN + n];
    }
    v += num / den;
  }
  v *= 0.25f;

  float mx = v;
#pragma unroll
  for (int o = 32; o; o >>= 1) mx = fmaxf(mx, __shfl_xor(mx, o));
  float p = exp2f((v - mx) * L2E);
  float sm = p;
#pragma unroll
  for (int o = 32; o; o >>= 1) sm += __shfl_xor(sm, o);
  out[(size_t)n * HD + lane] = p / sm;
}

extern "C" void kernel_launch(void* const* d_in, const int* in_sizes, int n_in,
                              void* d_out, int out_size, void* d_ws, size_t ws_size,
                              hipStream_t stream) {
  const float* F0 = (const float*)d_in[0];
  const float* E0 = (const float*)d_in[1];
  const int* A = (const int*)d_in[2];
  const float* Wf = (const float*)d_in[3];
  const float* We = (const float*)d_in[4];
  const float* a = (const float*)d_in[5];
  float* out = (float*)d_out;

  char* w = (char*)d_ws;
  float* esrc = (float*)w;        w += (size_t)NH * NN * 4;
  _Float16* edh = (_Float16*)w;   w += (size_t)NH * MM * 2;
  _Float16* ed2h = (_Float16*)w;  w += (size_t)NH * MM * 2;
  uint4* Bp = (uint4*)w;          w += (size_t)NH * HD * MM * 2;
  u32* bitsG = (u32*)w;           w += (size_t)NN * 256 * 4;
  float* Npart = (float*)w;       w += (size_t)16 * NN * HD * 4;
  float* Dpart = (float*)w;       w += (size_t)16 * NN * 4;

  k_prep<<<3200, 256, 0, stream>>>(A, bitsG, F0, Wf, a, esrc, E0, We, Bp, edh, ed2h);
  k_main<<<256, 1024, 0, stream>>>(bitsG, Bp, esrc, edh, ed2h, Npart, Dpart);
  k_comb<<<NN / 4, 256, 0, stream>>>(Npart, Dpart, out);
}